// Round 4
// baseline (299.135 us; speedup 1.0000x reference)
//
#include <hip/hip_runtime.h>

typedef __bf16 bf16x8 __attribute__((ext_vector_type(8)));
typedef __bf16 bf16x4 __attribute__((ext_vector_type(4)));
typedef float  f32x4  __attribute__((ext_vector_type(4)));

#define N_HEAD 12
#define HEAD   64
#define HID    768
#define SEQ    2048
#define BATCH  2
#define BH     (BATCH*N_HEAD)   // 24
#define MROWS  (BATCH*SEQ)      // 4096
#define SC2    0.18033688011112042f   // 0.125 * log2(e), folded into Q at gemm epilogue

static __device__ __forceinline__ f32x4 mfma32(bf16x8 a, bf16x8 b, f32x4 c) {
    return __builtin_amdgcn_mfma_f32_16x16x32_bf16(a, b, c, 0, 0, 0);
}

#define GLOAD_LDS16(gp, lp) __builtin_amdgcn_global_load_lds( \
    (const __attribute__((address_space(1))) void*)(gp), \
    (__attribute__((address_space(3))) void*)(lp), 16, 0, 0)

// ---------------- cast x (fp32 -> bf16), 8 elems/thread ----------------
__global__ __launch_bounds__(256) void cast_f32_bf16(const float* __restrict__ in,
                                                     __bf16* __restrict__ out, int n8) {
    int i = blockIdx.x * 256 + threadIdx.x;
    if (i >= n8) return;
    const float4* p = (const float4*)in;
    float4 a = p[2*i], b = p[2*i+1];
    bf16x8 o;
    o[0]=(__bf16)a.x; o[1]=(__bf16)a.y; o[2]=(__bf16)a.z; o[3]=(__bf16)a.w;
    o[4]=(__bf16)b.x; o[5]=(__bf16)b.y; o[6]=(__bf16)b.z; o[7]=(__bf16)b.w;
    *(bf16x8*)&out[(size_t)8*i] = o;
}

// ------------- transpose + cast: in[R][C] fp32 -> out[C][R] bf16 -------------
__global__ __launch_bounds__(256) void transpose_cast(const float* __restrict__ in,
                                                      __bf16* __restrict__ out, int R, int C) {
    __shared__ float t[32][33];
    int bx = blockIdx.x * 32;
    int by = blockIdx.y * 32;
    int x = threadIdx.x, y = threadIdx.y;  // (32, 8)
    #pragma unroll
    for (int i = 0; i < 32; i += 8) t[y+i][x] = in[(size_t)(by+y+i)*C + bx + x];
    __syncthreads();
    #pragma unroll
    for (int i = 0; i < 32; i += 8) out[(size_t)(bx+y+i)*R + by + x] = (__bf16)t[x][y+i];
}

// ---------------- MFMA GEMM, A[M][K] bf16, Bt[N][K] bf16 ----------------
// BK=64, global_load_lds(16B) into linear LDS, both-sides XOR swizzle.
template<int EPI>
__global__ __launch_bounds__(256) void gemm_bt(
    const __bf16* __restrict__ A, const __bf16* __restrict__ Bt,
    const float* __restrict__ bias, float* __restrict__ Cout,
    __bf16* __restrict__ Qo, __bf16* __restrict__ Ko, __bf16* __restrict__ Vo,
    int M, int N, int K)
{
    __shared__ __align__(16) __bf16 As[128*64];
    __shared__ __align__(16) __bf16 Bs[128*64];
    int tid = threadIdx.x;
    int m0 = blockIdx.y * 128, n0 = blockIdx.x * 128;
    int wave = tid >> 6, lane = tid & 63, lr = lane & 15, lk = lane >> 4;
    int wr = wave >> 1, wc = wave & 1;

    f32x4 acc[4][4];
    f32x4 zz = {0.f, 0.f, 0.f, 0.f};
    #pragma unroll
    for (int m = 0; m < 4; m++)
        #pragma unroll
        for (int n = 0; n < 4; n++) acc[m][n] = zz;

    for (int k0 = 0; k0 < K; k0 += 64) {
        #pragma unroll
        for (int i = 0; i < 4; i++) {
            int u = tid + 256*i;
            int row = u >> 3;
            int c = (u & 7) ^ (row & 7);
            GLOAD_LDS16(&A [(size_t)(m0+row)*K + k0 + c*8], &As[(size_t)u*8]);
            GLOAD_LDS16(&Bt[(size_t)(n0+row)*K + k0 + c*8], &Bs[(size_t)u*8]);
        }
        __syncthreads();
        #pragma unroll
        for (int kk = 0; kk < 2; kk++) {
            bf16x8 af[4], bfr[4];
            #pragma unroll
            for (int m = 0; m < 4; m++) {
                int row = wr*64 + m*16 + lr;
                int byte = (row*128 + kk*64 + lk*16) ^ ((row & 7) << 4);
                af[m] = *(const bf16x8*)((const char*)As + byte);
            }
            #pragma unroll
            for (int n = 0; n < 4; n++) {
                int row = wc*64 + n*16 + lr;
                int byte = (row*128 + kk*64 + lk*16) ^ ((row & 7) << 4);
                bfr[n] = *(const bf16x8*)((const char*)Bs + byte);
            }
            #pragma unroll
            for (int m = 0; m < 4; m++)
                #pragma unroll
                for (int n = 0; n < 4; n++)
                    acc[m][n] = mfma32(af[m], bfr[n], acc[m][n]);
        }
        __syncthreads();
    }

    #pragma unroll
    for (int m = 0; m < 4; m++)
    #pragma unroll
    for (int n = 0; n < 4; n++)
    #pragma unroll
    for (int r = 0; r < 4; r++) {
        int row = m0 + wr*64 + m*16 + lk*4 + r;
        int col = n0 + wc*64 + n*16 + lr;
        float v = acc[m][n][r] + bias[col];
        if (EPI == 0) {
            Cout[(size_t)row * N + col] = v;
        } else {
            int b_idx = row >> 11, s = row & 2047;
            int which = col / HID, hc = col % HID;
            int bh = b_idx * N_HEAD + (hc >> 6);
            int d = hc & 63;
            if (which == 0)      Qo[((size_t)bh*SEQ + s)*HEAD + d] = (__bf16)(v * SC2);
            else if (which == 1) Ko[((size_t)bh*SEQ + s)*HEAD + d] = (__bf16)v;
            else                 Vo[((size_t)bh*HEAD + d)*SEQ + s] = (__bf16)v;
        }
    }
}

// ---------------- causal flash attention ----------------
// 2 waves/block, KV tiles split by parity across waves; 32 q-rows/block.
// Swapped QK^T, static-max softmax (no max reduce, no rescale, zero per-tile
// shuffles), PV via K=32 MFMA with permuted-k fragment concat.
__global__ __launch_bounds__(128, 3) void flash_attn(
    const __bf16* __restrict__ Q, const __bf16* __restrict__ Km,
    const __bf16* __restrict__ Vt, __bf16* __restrict__ ctx)
{
    __shared__ float xch[2][64][24];
    int tid = threadIdx.x;
    int w = tid >> 6;            // kv parity this wave owns
    int lane = tid & 63;
    int lr = lane & 15, lk = lane >> 4;
    int gid = blockIdx.x;
    int bh = gid % BH;
    int qi = 63 - gid / BH;      // longest first
    int b_idx = bh / N_HEAD, h = bh % N_HEAD;
    int q0 = qi * 32;
    const size_t hb = (size_t)bh * SEQ * HEAD;
    const size_t vb = (size_t)bh * HEAD * SEQ;
    f32x4 zz = {0.f, 0.f, 0.f, 0.f};

    bf16x8 qf[2][2];
    #pragma unroll
    for (int rb = 0; rb < 2; rb++)
        #pragma unroll
        for (int kb = 0; kb < 2; kb++)
            qf[rb][kb] = *(const bf16x8*)&Q[hb + (size_t)(q0 + rb*16 + lr)*HEAD + kb*32 + lk*8];

    f32x4 acc[2][4];
    float lsum[2] = {0.f, 0.f};
    #pragma unroll
    for (int rb = 0; rb < 2; rb++)
        #pragma unroll
        for (int db = 0; db < 4; db++) acc[rb][db] = zz;

    int nt = (q0 + 95) >> 6;     // ceil((q0+32)/64)

    bf16x8 kf[4][2];
    {
        int kv0 = w * 64;
        #pragma unroll
        for (int cb = 0; cb < 4; cb++)
            #pragma unroll
            for (int kb = 0; kb < 2; kb++)
                kf[cb][kb] = *(const bf16x8*)&Km[hb + (size_t)(kv0 + cb*16 + lr)*HEAD + kb*32 + lk*8];
    }

    for (int t = w; t < nt; t += 2) {
        int kv0 = t * 64;

        // V fragments (B-operand, k permuted same as P): V[kv0+cb*16+lk*4+j][d]
        bf16x4 vf[4][4];
        #pragma unroll
        for (int db = 0; db < 4; db++)
            #pragma unroll
            for (int cb = 0; cb < 4; cb++)
                vf[db][cb] = *(const bf16x4*)&Vt[vb + (size_t)(db*16 + lr)*SEQ + kv0 + cb*16 + lk*4];

        // swapped QK^T: sc[rb][cb][r] = S2[q=q0+rb*16+lr][k=kv0+cb*16+lk*4+r] (exp2-domain)
        f32x4 sc[2][4];
        __builtin_amdgcn_s_setprio(1);
        #pragma unroll
        for (int rb = 0; rb < 2; rb++)
            #pragma unroll
            for (int cb = 0; cb < 4; cb++) {
                f32x4 z = mfma32(kf[cb][0], qf[rb][0], zz);
                sc[rb][cb] = mfma32(kf[cb][1], qf[rb][1], z);
            }
        __builtin_amdgcn_s_setprio(0);

        // prefetch this wave's next K tile
        if (t + 2 < nt) {
            int kv1 = (t + 2) * 64;
            #pragma unroll
            for (int cb = 0; cb < 4; cb++)
                #pragma unroll
                for (int kb = 0; kb < 2; kb++)
                    kf[cb][kb] = *(const bf16x8*)&Km[hb + (size_t)(kv1 + cb*16 + lr)*HEAD + kb*32 + lk*8];
        }

        // causal mask on diagonal-touching tiles only
        if (kv0 + 63 > q0) {
            #pragma unroll
            for (int rb = 0; rb < 2; rb++)
                #pragma unroll
                for (int cb = 0; cb < 4; cb++)
                    #pragma unroll
                    for (int r = 0; r < 4; r++) {
                        int kg = kv0 + cb*16 + lk*4 + r;
                        int qg = q0 + rb*16 + lr;
                        if (kg > qg) sc[rb][cb][r] = -30000.f;
                    }
        }

        #pragma unroll
        for (int rb = 0; rb < 2; rb++) {
            // static-max: P = exp2(sc) directly; per-lane partial row-sum
            bf16x8 pa[2];
            float rs = 0.f;
            #pragma unroll
            for (int cb = 0; cb < 4; cb++)
                #pragma unroll
                for (int r = 0; r < 4; r++) {
                    float p = exp2f(sc[rb][cb][r]);
                    rs += p;
                    pa[cb >> 1][(cb & 1)*4 + r] = (__bf16)p;
                }
            lsum[rb] += rs;

            __builtin_amdgcn_s_setprio(1);
            #pragma unroll
            for (int db = 0; db < 4; db++) {
                bf16x8 v01 = __builtin_shufflevector(vf[db][0], vf[db][1], 0,1,2,3,4,5,6,7);
                bf16x8 v23 = __builtin_shufflevector(vf[db][2], vf[db][3], 0,1,2,3,4,5,6,7);
                acc[rb][db] = mfma32(pa[0], v01, acc[rb][db]);
                acc[rb][db] = mfma32(pa[1], v23, acc[rb][db]);
            }
            __builtin_amdgcn_s_setprio(0);
        }
    }

    // cross-wave combine: wave w finalizes rb=w, gives away rb=1-w
    int keep = w, give = 1 - w;
    #pragma unroll
    for (int db = 0; db < 4; db++)
        *(f32x4*)&xch[w][lane][db*4] = acc[give][db];
    xch[w][lane][16] = lsum[give];
    __syncthreads();
    #pragma unroll
    for (int db = 0; db < 4; db++)
        acc[keep][db] += *(const f32x4*)&xch[give][lane][db*4];

    float rs = lsum[keep] + xch[give][lane][16];
    rs += __shfl_xor(rs, 16);
    rs += __shfl_xor(rs, 32);
    float rl = 1.0f / rs;
    float li[4];
    #pragma unroll
    for (int r = 0; r < 4; r++)
        li[r] = __shfl(rl, (lane & 48) | (lk*4 + r));

    #pragma unroll
    for (int db = 0; db < 4; db++)
        #pragma unroll
        for (int r = 0; r < 4; r++) {
            int qg = q0 + keep*16 + lk*4 + r;
            int d = db*16 + lr;
            ctx[((size_t)(b_idx*SEQ + qg))*HID + h*HEAD + d] = (__bf16)(acc[keep][db][r] * li[r]);
        }
}

// ---------------- launch ----------------
extern "C" void kernel_launch(void* const* d_in, const int* in_sizes, int n_in,
                              void* d_out, int out_size, void* d_ws, size_t ws_size,
                              hipStream_t stream) {
    const float* x  = (const float*)d_in[0];   // [2,2048,768]
    const float* w1 = (const float*)d_in[1];   // [768,2304]
    const float* b1 = (const float*)d_in[2];   // [2304]
    const float* w2 = (const float*)d_in[3];   // [768,768]
    const float* b2 = (const float*)d_in[4];   // [768]
    float* out = (float*)d_out;

    char* ws = (char*)d_ws;
    size_t o = 0;
    __bf16* Xb  = (__bf16*)(ws + o); o += (size_t)MROWS*HID*2;
    __bf16* W1t = (__bf16*)(ws + o); o += (size_t)3*HID*HID*2;
    __bf16* W2t = (__bf16*)(ws + o); o += (size_t)HID*HID*2;
    __bf16* Qb  = (__bf16*)(ws + o); o += (size_t)MROWS*HID*2;
    __bf16* Kb  = (__bf16*)(ws + o); o += (size_t)MROWS*HID*2;
    __bf16* Vt  = (__bf16*)(ws + o); o += (size_t)MROWS*HID*2;
    __bf16* CTX = (__bf16*)(ws + o); o += (size_t)MROWS*HID*2;

    cast_f32_bf16<<<(MROWS*HID/8 + 255)/256, 256, 0, stream>>>(x, Xb, MROWS*HID/8);
    transpose_cast<<<dim3(3*HID/32, HID/32), dim3(32, 8), 0, stream>>>(w1, W1t, HID, 3*HID);
    transpose_cast<<<dim3(HID/32,   HID/32), dim3(32, 8), 0, stream>>>(w2, W2t, HID, HID);

    gemm_bt<1><<<dim3(3*HID/128, MROWS/128), 256, 0, stream>>>(
        Xb, W1t, b1, nullptr, Qb, Kb, Vt, MROWS, 3*HID, HID);

    flash_attn<<<dim3(64*BH), 128, 0, stream>>>(Qb, Kb, Vt, CTX);

    gemm_bt<0><<<dim3(HID/128, MROWS/128), 256, 0, stream>>>(
        CTX, W2t, b2, out, nullptr, nullptr, nullptr, MROWS, HID, HID);
}

// Round 5
// 218.637 us; speedup vs baseline: 1.3682x; 1.3682x over previous
//
#include <hip/hip_runtime.h>

typedef __bf16 bf16x8 __attribute__((ext_vector_type(8)));
typedef __bf16 bf16x4 __attribute__((ext_vector_type(4)));
typedef float  f32x4  __attribute__((ext_vector_type(4)));

#define N_HEAD 12
#define HEAD   64
#define HID    768
#define SEQ    2048
#define BATCH  2
#define BH     (BATCH*N_HEAD)   // 24
#define MROWS  (BATCH*SEQ)      // 4096
#define SC2    0.18033688011112042f   // 0.125 * log2(e), folded into Q at gemm epilogue

static __device__ __forceinline__ f32x4 mfma32(bf16x8 a, bf16x8 b, f32x4 c) {
    return __builtin_amdgcn_mfma_f32_16x16x32_bf16(a, b, c, 0, 0, 0);
}

#define GLOAD_LDS16(gp, lp) __builtin_amdgcn_global_load_lds( \
    (const __attribute__((address_space(1))) void*)(gp), \
    (__attribute__((address_space(3))) void*)(lp), 16, 0, 0)

// ---------------- cast x (fp32 -> bf16), 8 elems/thread ----------------
__global__ __launch_bounds__(256) void cast_f32_bf16(const float* __restrict__ in,
                                                     __bf16* __restrict__ out, int n8) {
    int i = blockIdx.x * 256 + threadIdx.x;
    if (i >= n8) return;
    const float4* p = (const float4*)in;
    float4 a = p[2*i], b = p[2*i+1];
    bf16x8 o;
    o[0]=(__bf16)a.x; o[1]=(__bf16)a.y; o[2]=(__bf16)a.z; o[3]=(__bf16)a.w;
    o[4]=(__bf16)b.x; o[5]=(__bf16)b.y; o[6]=(__bf16)b.z; o[7]=(__bf16)b.w;
    *(bf16x8*)&out[(size_t)8*i] = o;
}

// ------------- transpose + cast: in[R][C] fp32 -> out[C][R] bf16 -------------
__global__ __launch_bounds__(256) void transpose_cast(const float* __restrict__ in,
                                                      __bf16* __restrict__ out, int R, int C) {
    __shared__ float t[32][33];
    int bx = blockIdx.x * 32;
    int by = blockIdx.y * 32;
    int x = threadIdx.x, y = threadIdx.y;  // (32, 8)
    #pragma unroll
    for (int i = 0; i < 32; i += 8) t[y+i][x] = in[(size_t)(by+y+i)*C + bx + x];
    __syncthreads();
    #pragma unroll
    for (int i = 0; i < 32; i += 8) out[(size_t)(bx+y+i)*R + by + x] = (__bf16)t[x][y+i];
}

// ---------------- MFMA GEMM, A[M][K] bf16, Bt[N][K] bf16 ----------------
template<int EPI>
__global__ __launch_bounds__(256) void gemm_bt(
    const __bf16* __restrict__ A, const __bf16* __restrict__ Bt,
    const float* __restrict__ bias, float* __restrict__ Cout,
    __bf16* __restrict__ Qo, __bf16* __restrict__ Ko, __bf16* __restrict__ Vo,
    int M, int N, int K)
{
    __shared__ __align__(16) __bf16 As[128*64];
    __shared__ __align__(16) __bf16 Bs[128*64];
    int tid = threadIdx.x;
    int m0 = blockIdx.y * 128, n0 = blockIdx.x * 128;
    int wave = tid >> 6, lane = tid & 63, lr = lane & 15, lk = lane >> 4;
    int wr = wave >> 1, wc = wave & 1;

    f32x4 acc[4][4];
    f32x4 zz = {0.f, 0.f, 0.f, 0.f};
    #pragma unroll
    for (int m = 0; m < 4; m++)
        #pragma unroll
        for (int n = 0; n < 4; n++) acc[m][n] = zz;

    for (int k0 = 0; k0 < K; k0 += 64) {
        #pragma unroll
        for (int i = 0; i < 4; i++) {
            int u = tid + 256*i;
            int row = u >> 3;
            int c = (u & 7) ^ (row & 7);
            GLOAD_LDS16(&A [(size_t)(m0+row)*K + k0 + c*8], &As[(size_t)u*8]);
            GLOAD_LDS16(&Bt[(size_t)(n0+row)*K + k0 + c*8], &Bs[(size_t)u*8]);
        }
        __syncthreads();
        #pragma unroll
        for (int kk = 0; kk < 2; kk++) {
            bf16x8 af[4], bfr[4];
            #pragma unroll
            for (int m = 0; m < 4; m++) {
                int row = wr*64 + m*16 + lr;
                int byte = (row*128 + kk*64 + lk*16) ^ ((row & 7) << 4);
                af[m] = *(const bf16x8*)((const char*)As + byte);
            }
            #pragma unroll
            for (int n = 0; n < 4; n++) {
                int row = wc*64 + n*16 + lr;
                int byte = (row*128 + kk*64 + lk*16) ^ ((row & 7) << 4);
                bfr[n] = *(const bf16x8*)((const char*)Bs + byte);
            }
            #pragma unroll
            for (int m = 0; m < 4; m++)
                #pragma unroll
                for (int n = 0; n < 4; n++)
                    acc[m][n] = mfma32(af[m], bfr[n], acc[m][n]);
        }
        __syncthreads();
    }

    #pragma unroll
    for (int m = 0; m < 4; m++)
    #pragma unroll
    for (int n = 0; n < 4; n++)
    #pragma unroll
    for (int r = 0; r < 4; r++) {
        int row = m0 + wr*64 + m*16 + lk*4 + r;
        int col = n0 + wc*64 + n*16 + lr;
        float v = acc[m][n][r] + bias[col];
        if (EPI == 0) {
            Cout[(size_t)row * N + col] = v;
        } else {
            int b_idx = row >> 11, s = row & 2047;
            int which = col / HID, hc = col % HID;
            int bh = b_idx * N_HEAD + (hc >> 6);
            int d = hc & 63;
            if (which == 0)      Qo[((size_t)bh*SEQ + s)*HEAD + d] = (__bf16)(v * SC2);
            else if (which == 1) Ko[((size_t)bh*SEQ + s)*HEAD + d] = (__bf16)v;
            else                 Vo[((size_t)bh*HEAD + d)*SEQ + s] = (__bf16)v;
        }
    }
}

// ---------------- causal flash attention ----------------
// 2 waves/block (kv-tile parity split), 32 q-rows/block. Swapped QK^T,
// static-max softmax (zero per-tile shuffles), K=32 PV with permuted-k concat.
// ALL register arrays statically indexed (rule #20: no runtime idx -> no scratch).
__global__ __launch_bounds__(128, 3) void flash_attn(
    const __bf16* __restrict__ Q, const __bf16* __restrict__ Km,
    const __bf16* __restrict__ Vt, __bf16* __restrict__ ctx)
{
    __shared__ float xch[2][64][20];
    int tid = threadIdx.x;
    int w = tid >> 6;            // kv parity this wave owns
    int lane = tid & 63;
    int lr = lane & 15, lk = lane >> 4;
    int gid = blockIdx.x;
    int bh = gid % BH;
    int qi = 63 - gid / BH;      // longest first
    int b_idx = bh / N_HEAD, h = bh % N_HEAD;
    int q0 = qi * 32;
    const size_t hb = (size_t)bh * SEQ * HEAD;
    const size_t vb = (size_t)bh * HEAD * SEQ;
    f32x4 zz = {0.f, 0.f, 0.f, 0.f};

    bf16x8 qf0[2], qf1[2];
    #pragma unroll
    for (int kb = 0; kb < 2; kb++) {
        qf0[kb] = *(const bf16x8*)&Q[hb + (size_t)(q0 + lr)*HEAD + kb*32 + lk*8];
        qf1[kb] = *(const bf16x8*)&Q[hb + (size_t)(q0 + 16 + lr)*HEAD + kb*32 + lk*8];
    }

    f32x4 acc0[4], acc1[4];
    float ls0 = 0.f, ls1 = 0.f;
    #pragma unroll
    for (int db = 0; db < 4; db++) { acc0[db] = zz; acc1[db] = zz; }

    int nt = (q0 + 95) >> 6;     // ceil((q0+32)/64)

    bf16x8 kf[4][2];
    {
        int kv0 = w * 64;
        #pragma unroll
        for (int cb = 0; cb < 4; cb++)
            #pragma unroll
            for (int kb = 0; kb < 2; kb++)
                kf[cb][kb] = *(const bf16x8*)&Km[hb + (size_t)(kv0 + cb*16 + lr)*HEAD + kb*32 + lk*8];
    }

    for (int t = w; t < nt; t += 2) {
        int kv0 = t * 64;
        const __bf16* vtile = &Vt[vb + kv0];

        // swapped QK^T: scR[cb][r] = S2[q=q0+R*16+lr][k=kv0+cb*16+lk*4+r]
        f32x4 sc0[4], sc1[4];
        __builtin_amdgcn_s_setprio(1);
        #pragma unroll
        for (int cb = 0; cb < 4; cb++) {
            f32x4 z0 = mfma32(kf[cb][0], qf0[0], zz);
            sc0[cb] = mfma32(kf[cb][1], qf0[1], z0);
            f32x4 z1 = mfma32(kf[cb][0], qf1[0], zz);
            sc1[cb] = mfma32(kf[cb][1], qf1[1], z1);
        }
        __builtin_amdgcn_s_setprio(0);

        // prefetch this wave's next K tile
        if (t + 2 < nt) {
            int kv1 = (t + 2) * 64;
            #pragma unroll
            for (int cb = 0; cb < 4; cb++)
                #pragma unroll
                for (int kb = 0; kb < 2; kb++)
                    kf[cb][kb] = *(const bf16x8*)&Km[hb + (size_t)(kv1 + cb*16 + lr)*HEAD + kb*32 + lk*8];
        }

        // causal mask on diagonal-touching tiles only
        if (kv0 + 63 > q0) {
            #pragma unroll
            for (int cb = 0; cb < 4; cb++)
                #pragma unroll
                for (int r = 0; r < 4; r++) {
                    int kg = kv0 + cb*16 + lk*4 + r;
                    if (kg > q0 + lr)      sc0[cb][r] = -30000.f;
                    if (kg > q0 + 16 + lr) sc1[cb][r] = -30000.f;
                }
        }

        // static-max softmax: P = exp2(sc); per-lane partial row-sums
        bf16x8 pa0[2], pa1[2];
        {
            float rs0 = 0.f, rs1 = 0.f;
            #pragma unroll
            for (int cb = 0; cb < 4; cb++)
                #pragma unroll
                for (int r = 0; r < 4; r++) {
                    float p0 = exp2f(sc0[cb][r]);
                    float p1 = exp2f(sc1[cb][r]);
                    rs0 += p0; rs1 += p1;
                    pa0[cb >> 1][(cb & 1)*4 + r] = (__bf16)p0;
                    pa1[cb >> 1][(cb & 1)*4 + r] = (__bf16)p1;
                }
            ls0 += rs0; ls1 += rs1;
        }

        // PV: K=32 MFMA, V loaded per-db (L2-resident)
        #pragma unroll
        for (int db = 0; db < 4; db++) {
            const __bf16* vrow = vtile + (size_t)(db*16 + lr)*SEQ;
            bf16x4 a0 = *(const bf16x4*)&vrow[lk*4];
            bf16x4 a1 = *(const bf16x4*)&vrow[16 + lk*4];
            bf16x4 a2 = *(const bf16x4*)&vrow[32 + lk*4];
            bf16x4 a3 = *(const bf16x4*)&vrow[48 + lk*4];
            bf16x8 v01 = __builtin_shufflevector(a0, a1, 0,1,2,3,4,5,6,7);
            bf16x8 v23 = __builtin_shufflevector(a2, a3, 0,1,2,3,4,5,6,7);
            __builtin_amdgcn_s_setprio(1);
            acc0[db] = mfma32(pa0[0], v01, acc0[db]);
            acc0[db] = mfma32(pa0[1], v23, acc0[db]);
            acc1[db] = mfma32(pa1[0], v01, acc1[db]);
            acc1[db] = mfma32(pa1[1], v23, acc1[db]);
            __builtin_amdgcn_s_setprio(0);
        }
    }

    // cross-wave combine (wave 0 keeps rb0, wave 1 keeps rb1) — static indices only
    if (w == 0) {
        #pragma unroll
        for (int db = 0; db < 4; db++) *(f32x4*)&xch[0][lane][db*4] = acc1[db];
        xch[0][lane][16] = ls1;
    } else {
        #pragma unroll
        for (int db = 0; db < 4; db++) *(f32x4*)&xch[1][lane][db*4] = acc0[db];
        xch[1][lane][16] = ls0;
    }
    __syncthreads();

    f32x4 accF[4];
    float lsF;
    if (w == 0) {
        #pragma unroll
        for (int db = 0; db < 4; db++) accF[db] = acc0[db] + *(const f32x4*)&xch[1][lane][db*4];
        lsF = ls0 + xch[1][lane][16];
    } else {
        #pragma unroll
        for (int db = 0; db < 4; db++) accF[db] = acc1[db] + *(const f32x4*)&xch[0][lane][db*4];
        lsF = ls1 + xch[0][lane][16];
    }

    float rs = lsF;
    rs += __shfl_xor(rs, 16);
    rs += __shfl_xor(rs, 32);
    float rl = 1.0f / rs;
    float li[4];
    #pragma unroll
    for (int r = 0; r < 4; r++)
        li[r] = __shfl(rl, (lane & 48) | (lk*4 + r));

    #pragma unroll
    for (int db = 0; db < 4; db++)
        #pragma unroll
        for (int r = 0; r < 4; r++) {
            int qg = q0 + w*16 + lk*4 + r;
            int d = db*16 + lr;
            ctx[((size_t)(b_idx*SEQ + qg))*HID + h*HEAD + d] = (__bf16)(accF[db][r] * li[r]);
        }
}

// ---------------- launch ----------------
extern "C" void kernel_launch(void* const* d_in, const int* in_sizes, int n_in,
                              void* d_out, int out_size, void* d_ws, size_t ws_size,
                              hipStream_t stream) {
    const float* x  = (const float*)d_in[0];   // [2,2048,768]
    const float* w1 = (const float*)d_in[1];   // [768,2304]
    const float* b1 = (const float*)d_in[2];   // [2304]
    const float* w2 = (const float*)d_in[3];   // [768,768]
    const float* b2 = (const float*)d_in[4];   // [768]
    float* out = (float*)d_out;

    char* ws = (char*)d_ws;
    size_t o = 0;
    __bf16* Xb  = (__bf16*)(ws + o); o += (size_t)MROWS*HID*2;
    __bf16* W1t = (__bf16*)(ws + o); o += (size_t)3*HID*HID*2;
    __bf16* W2t = (__bf16*)(ws + o); o += (size_t)HID*HID*2;
    __bf16* Qb  = (__bf16*)(ws + o); o += (size_t)MROWS*HID*2;
    __bf16* Kb  = (__bf16*)(ws + o); o += (size_t)MROWS*HID*2;
    __bf16* Vt  = (__bf16*)(ws + o); o += (size_t)MROWS*HID*2;
    __bf16* CTX = (__bf16*)(ws + o); o += (size_t)MROWS*HID*2;

    cast_f32_bf16<<<(MROWS*HID/8 + 255)/256, 256, 0, stream>>>(x, Xb, MROWS*HID/8);
    transpose_cast<<<dim3(3*HID/32, HID/32), dim3(32, 8), 0, stream>>>(w1, W1t, HID, 3*HID);
    transpose_cast<<<dim3(HID/32,   HID/32), dim3(32, 8), 0, stream>>>(w2, W2t, HID, HID);

    gemm_bt<1><<<dim3(3*HID/128, MROWS/128), 256, 0, stream>>>(
        Xb, W1t, b1, nullptr, Qb, Kb, Vt, MROWS, 3*HID, HID);

    flash_attn<<<dim3(64*BH), 128, 0, stream>>>(Qb, Kb, Vt, CTX);

    gemm_bt<0><<<dim3(HID/128, MROWS/128), 256, 0, stream>>>(
        CTX, W2t, b2, out, nullptr, nullptr, nullptr, MROWS, HID, HID);
}